// Round 1
// 232.549 us; speedup vs baseline: 1.0242x; 1.0242x over previous
//
#include <hip/hip_runtime.h>

// BindingFormer fused pipeline for MI355X (gfx950), round 7.
// r6 post-mortem: edge_k 103us, MfmaUtil 20%, VALUBusy 36%, HBM 14% — work
// problem, not roofline. 84% of GEMM1's K (512/608) is gathered rep rows,
// recomputed ~260x per node. Fix: factor the linear term — precompute
// PROJ_S = REP @ W1_src, PROJ_D = REP @ W1_dst per NODE (268 MFLOP, new
// proj_k reusing w1f k-tiles 3..18), gather f32 proj rows in the H epilogue
// instead of running them through per-edge MFMA. GEMM1 K 608->96, LDS
// 77.5->34 KB, rep gather+staging deleted. Also: GEMM2 wave mapping now
// writes full 128-B output lines per wave (WRITE_SIZE was 1.53x ideal).

typedef __attribute__((ext_vector_type(8))) short short8;  // 8 x bf16 (4 VGPRs)
typedef __attribute__((ext_vector_type(4))) float f32x4;   // MFMA accumulator

#define TWO_PI 6.283185307179586f
#define E_AB_TOT 131072

// ws layout (bytes)
#define WS_RT    0         // frames: 1024 x 12 f32            = 49152
#define WS_REPB  49152     // rep bf16 1024x256                = 524288
#define WS_W1F   573440    // swizzled W1' 19*16*64*8 bf16     = 311296
#define WS_W2F   884736    // swizzled W2  8*8*64*8 bf16       = 65536
#define WS_PS    950272    // PROJ_S f32 1024x256              = 1048576
#define WS_PD    1998848   // PROJ_D f32 1024x256              = 1048576

__device__ __forceinline__ unsigned short f2bf(float x){
  unsigned int u = __float_as_uint(x);
  u += 0x7fffu + ((u >> 16) & 1u);            // RTNE
  return (unsigned short)(u >> 16);
}

// pack two f32 -> two bf16 (RTNE) in one u32 via v_perm
__device__ __forceinline__ unsigned int pack_bf16(float lo, float hi){
  unsigned int ul = __float_as_uint(lo), uh = __float_as_uint(hi);
  ul += 0x7fffu + ((ul >> 16) & 1u);
  uh += 0x7fffu + ((uh >> 16) & 1u);
  return __builtin_amdgcn_perm(uh, ul, 0x07060302);  // {uh[31:16], ul[31:16]}
}

// gelu tanh-form == x * sigmoid(2z), z = 0.79788456(x + 0.044715 x^3)
// exp(-2z) = exp2(x * (a + b*x^2)), a = -2.30220847, b = a*0.044715
__device__ __forceinline__ float gelu_s(float x){
  float s = x * x;
  float w = x * __builtin_fmaf(-0.1029437f, s, -2.30220847f);
  float e = __builtin_exp2f(w);
  return x * __builtin_amdgcn_rcpf(1.0f + e);
}

// ---------- merged prep: rep MLP (blk 0-127) | frames (128-131) |
//            swz2 (132-147) | swz1 w/ inline wg1 (148-223) -------------------
__global__ __launch_bounds__(256) void prep_k(
    const float* __restrict__ emb, const float* __restrict__ ts,
    const float* __restrict__ tf,  const float* __restrict__ w1,
    const float* __restrict__ b1,  const float* __restrict__ w2,
    const float* __restrict__ b2,  unsigned short* __restrict__ repb,
    const float* __restrict__ coords, float* __restrict__ RT,
    const float* __restrict__ wg, const float* __restrict__ w1e,
    unsigned short* __restrict__ w1f,
    const float* __restrict__ w2e, unsigned short* __restrict__ w2f){
  __shared__ float xt[288 * 12];   // rep part only
  __shared__ float ht[256 * 12];
  int blk = blockIdx.x, tid = threadIdx.x;
  if (blk < 128){                   // ---- node MLP, 8 nodes/block ----
    int n0 = blk * 8;
    #pragma unroll
    for (int nd = 0; nd < 8; ++nd)
      xt[tid * 12 + nd] = emb[(n0 + nd) * 256 + tid];
    {
      int nd = tid >> 5, j = tid & 31;
      float ang = TWO_PI * ts[n0 + nd] * tf[j & 15];
      float s, c; __sincosf(ang, &s, &c);
      xt[(256 + j) * 12 + nd] = (j < 16) ? s : c;
    }
    __syncthreads();
    float acc[8];
    float bias1 = b1[tid];
    #pragma unroll
    for (int nd = 0; nd < 8; ++nd) acc[nd] = bias1;
    #pragma unroll 4
    for (int k = 0; k < 288; ++k){
      float w = w1[k * 256 + tid];
      f32x4 xa = *(const f32x4*)&xt[k * 12];
      f32x4 xb = *(const f32x4*)&xt[k * 12 + 4];
      acc[0] += xa[0]*w; acc[1] += xa[1]*w; acc[2] += xa[2]*w; acc[3] += xa[3]*w;
      acc[4] += xb[0]*w; acc[5] += xb[1]*w; acc[6] += xb[2]*w; acc[7] += xb[3]*w;
    }
    #pragma unroll
    for (int nd = 0; nd < 8; ++nd) ht[tid * 12 + nd] = gelu_s(acc[nd]);
    __syncthreads();
    float acc2[8];
    float bias2 = b2[tid];
    #pragma unroll
    for (int nd = 0; nd < 8; ++nd) acc2[nd] = bias2;
    #pragma unroll 4
    for (int k = 0; k < 256; ++k){
      float w = w2[k * 256 + tid];
      f32x4 ha = *(const f32x4*)&ht[k * 12];
      f32x4 hb = *(const f32x4*)&ht[k * 12 + 4];
      acc2[0] += ha[0]*w; acc2[1] += ha[1]*w; acc2[2] += ha[2]*w; acc2[3] += ha[3]*w;
      acc2[4] += hb[0]*w; acc2[5] += hb[1]*w; acc2[6] += hb[2]*w; acc2[7] += hb[3]*w;
    }
    #pragma unroll
    for (int nd = 0; nd < 8; ++nd)
      repb[(n0 + nd) * 256 + tid] = f2bf(acc2[nd] + xt[tid * 12 + nd]);
  } else if (blk < 132){            // ---- frames ----
    int n = (blk - 128) * 256 + tid;
    const float* p = coords + n * 9;
    float ax=p[0],ay=p[1],az=p[2], bx=p[3],by=p[4],bz=p[5], cx=p[6],cy=p[7],cz=p[8];
    float v1x=cx-bx, v1y=cy-by, v1z=cz-bz;
    float v2x=ax-bx, v2y=ay-by, v2z=az-bz;
    float n1 = sqrtf(v1x*v1x+v1y*v1y+v1z*v1z) + 1e-6f;
    float e1x=v1x/n1, e1y=v1y/n1, e1z=v1z/n1;
    float dp = e1x*v2x + e1y*v2y + e1z*v2z;
    float u2x=v2x-e1x*dp, u2y=v2y-e1y*dp, u2z=v2z-e1z*dp;
    float n2 = sqrtf(u2x*u2x+u2y*u2y+u2z*u2z) + 1e-6f;
    float e2x=u2x/n2, e2y=u2y/n2, e2z=u2z/n2;
    float* r = RT + n * 12;
    r[0]=e1x; r[1]=e2x; r[2]=e1y*e2z - e1z*e2y;
    r[3]=e1y; r[4]=e2y; r[5]=e1z*e2x - e1x*e2z;
    r[6]=e1z; r[7]=e2z; r[8]=e1x*e2y - e1y*e2x;
    r[9]=bx;  r[10]=by; r[11]=bz;
  } else if (blk < 148){            // ---- swz2: W2 (256x128) -> frag ----
    int u = (blk - 132) * 4 + (tid >> 6);   // 0..63
    int lane = tid & 63;
    int s = u >> 3, c = u & 7;
    int n  = c * 16 + (lane & 15);
    int kb = s * 32 + (lane >> 4) * 8;
    unsigned short* o = w2f + (((s * 8 + c) * 64) + lane) * 8;
    for (int j = 0; j < 8; ++j)
      o[j] = f2bf(w2e[(kb + j) * 128 + n]);
  } else {                          // ---- swz1: W1' (608x256) -> frag ----
    // K: [0:27 geom=wg@w1e[0:128] | 27:91 rope (w1e 128:192) | 91:96 zero
    //     | 96:352 rep_src (192:448) | 352:608 rep_dst (448:704)]
    int u = (blk - 148) * 4 + (tid >> 6);   // 0..303
    int lane = tid & 63;
    int s = u >> 4, c = u & 15;
    int n  = c * 16 + (lane & 15);
    int kb = s * 32 + (lane >> 4) * 8;
    unsigned short* o = w1f + (((s * 16 + c) * 64) + lane) * 8;
    for (int j = 0; j < 8; ++j){
      int k = kb + j;
      float val;
      if (k < 27){                  // inline wg1: w_geom[k] . w1e[0:128, n]
        val = 0.f;
        for (int j2 = 0; j2 < 128; ++j2) val += wg[k * 128 + j2] * w1e[j2 * 256 + n];
      }
      else if (k < 91)  val = w1e[(128 + k - 27)  * 256 + n];
      else if (k < 96)  val = 0.f;
      else if (k < 352) val = w1e[(192 + k - 96)  * 256 + n];
      else              val = w1e[(448 + k - 352) * 256 + n];
      o[j] = f2bf(val);
    }
  }
}

// ---------- proj_k: per-node projections PROJ_S/PROJ_D = REP @ W1_{src,dst} --
// Reuses w1f A-frags (k-tiles 3..10 = rep_src, 11..18 = rep_dst) and REPB rows
// as B-frags. grid 32: blk = nt*2 + part. Output f32 [1024][256].
__global__ __launch_bounds__(512) void proj_k(
    const unsigned short* __restrict__ repb,
    const unsigned short* __restrict__ w1f,
    float* __restrict__ ps, float* __restrict__ pd)
{
  int part = blockIdx.x & 1;        // 0 = src (s 3..10), 1 = dst (s 11..18)
  int nt   = blockIdx.x >> 1;      // node tile, 64 nodes
  int tid  = threadIdx.x, w = tid >> 6, lane = tid & 63;
  int c0 = w * 2, lr = lane & 15, quad = lane >> 4;
  int n0g = nt * 64;
  const short8* w1f8 = (const short8*)w1f;
  f32x4 acc[8];
  #pragma unroll
  for (int i = 0; i < 8; ++i) acc[i] = (f32x4){0.f, 0.f, 0.f, 0.f};
  int sb = 3 + part * 8;
  #pragma unroll
  for (int s = 0; s < 8; ++s){
    short8 a0 = w1f8[((sb + s) * 16 + c0 + 0) * 64 + lane];
    short8 a1 = w1f8[((sb + s) * 16 + c0 + 1) * 64 + lane];
    #pragma unroll
    for (int t = 0; t < 4; ++t){
      short8 b = *(const short8*)(repb + (n0g + t * 16 + lr) * 256 + s * 32 + quad * 8);
      acc[t]     = __builtin_amdgcn_mfma_f32_16x16x32_bf16(a0, b, acc[t],     0, 0, 0);
      acc[4 + t] = __builtin_amdgcn_mfma_f32_16x16x32_bf16(a1, b, acc[4 + t], 0, 0, 0);
    }
  }
  float* out = part ? pd : ps;
  #pragma unroll
  for (int c = 0; c < 2; ++c){
    int n = (c0 + c) * 16 + quad * 4;
    #pragma unroll
    for (int t = 0; t < 4; ++t)
      *(f32x4*)(out + (n0g + t * 16 + lr) * 256 + n) = acc[c * 4 + t];
  }
}

// ---------- fused edge kernel: 64 edges/block, 512 thr (8 waves) -----------
// TRANSPOSED: mfma(A=weight frag, B=edge/H row frag) -> D[col=edge, row=n].
// GEMM1 now K=96 (3 k-tiles); rep contribution gathered from PROJ_S/PROJ_D
// (f32, L2-resident) in the H epilogue. GEMM2: wave owns 2 adjacent n-tiles
// x 2 e-tiles -> full 128-B output lines per wave.
__global__ __launch_bounds__(512, 4) void edge_k(
    const float* __restrict__ RT,  const float* __restrict__ cf,
    const int* __restrict__ resi, const int* __restrict__ chain,
    const int* __restrict__ gia,  const int* __restrict__ gib,
    const int* __restrict__ pid,
    const unsigned short* __restrict__ w1f, const unsigned short* __restrict__ w2f,
    const float* __restrict__ ps, const float* __restrict__ pd,
    const float* __restrict__ bias1, const float* __restrict__ bias2,
    float* __restrict__ outp)
{
  // phase1: edge_in 64 x 208 B (96 bf16 + pad); phase2 alias: H 64 x 528 B
  __shared__ __align__(16) char smem[33792];
  __shared__ int lsrc[64];
  __shared__ int ldst[64];

  int tid = threadIdx.x;
  int e0  = blockIdx.x * 64;

  if (tid < 64){
    int e = e0 + tid, s_, d_;
    if (e < E_AB_TOT){ s_ = gia[e]; d_ = gib[e]; }
    else {
      int i = e - E_AB_TOT;
      int b = i >> 10, w_ = i & 1023;
      s_ = pid[b * 32 + (w_ >> 5)];
      d_ = pid[b * 32 + (w_ & 31)];
    }
    lsrc[tid] = s_; ldst[tid] = d_;
  }
  __syncthreads();

  // features: 8 threads/edge, 12 cols each (cols 0..95)
  {
    int ed = tid >> 3, slot = tid & 7;
    int s_ = lsrc[ed], d_ = ldst[ed];
    unsigned short* row = (unsigned short*)(smem + ed * 208);
    float disp = ((float)resi[s_] - (float)resi[d_]) * 0.125f;
    float inv  = (chain[s_] == chain[d_]) ? 1.f / (fabsf(disp) + 1.f) : 0.f;
    const float* Rs = RT + s_ * 12;
    const float* Rd = RT + d_ * 12;
    float dx = Rd[9]-Rs[9], dy = Rd[10]-Rs[10], dz = Rd[11]-Rs[11];
    float dist = sqrtf(dx*dx + dy*dy + dz*dz + 1e-6f);
    float invd = 1.f / (dist + 1.f);
    #pragma unroll
    for (int q = 0; q < 12; ++q){
      int c = slot * 12 + q;
      float val;
      if (c < 15){                               // rbf
        float z = (dist - (float)c * (20.f / 14.f)) * (15.f / 20.f);
        val = __expf(-0.5f * z * z);
      } else if (c < 24){                        // relrot (a-major)
        int idx = c - 15, a = idx / 3, b_ = idx - a * 3;
        val = Rs[a]*Rd[b_] + Rs[3+a]*Rd[3+b_] + Rs[6+a]*Rd[6+b_];
      } else if (c < 27){                        // local
        int k = c - 24;
        val = (Rs[k]*dx + Rs[3+k]*dy + Rs[6+k]*dz) * invd;
      } else if (c < 91){                        // rope
        int j2 = c - 27;
        float ang = TWO_PI * disp * cf[j2 & 31];
        val = ((j2 < 32) ? __sinf(ang) : __cosf(ang)) * inv;
      } else val = 0.f;
      row[c] = f2bf(val);
    }
  }
  __syncthreads();

  // ---- GEMM1 (transposed): D[n][e] = W1_feat^T x edge_in^T, K=96 ----
  int w    = tid >> 6, lane = tid & 63;
  int c0   = w * 2;                 // 2 n-tiles per wave
  int lr   = lane & 15;             // edge within e-tile
  int quad = lane >> 4, qoff = quad * 16;
  f32x4 acc[8];                     // [c*4 + etile]
  #pragma unroll
  for (int i = 0; i < 8; ++i) acc[i] = (f32x4){0.f, 0.f, 0.f, 0.f};
  const short8* w1f8 = (const short8*)w1f;

  #pragma unroll
  for (int s = 0; s < 3; ++s){
    short8 a0 = w1f8[(s * 16 + c0 + 0) * 64 + lane];
    short8 a1 = w1f8[(s * 16 + c0 + 1) * 64 + lane];
    short8 be0 = *(const short8*)(smem + ( 0 + lr) * 208 + s * 64 + qoff);
    short8 be1 = *(const short8*)(smem + (16 + lr) * 208 + s * 64 + qoff);
    short8 be2 = *(const short8*)(smem + (32 + lr) * 208 + s * 64 + qoff);
    short8 be3 = *(const short8*)(smem + (48 + lr) * 208 + s * 64 + qoff);
    acc[0] = __builtin_amdgcn_mfma_f32_16x16x32_bf16(a0, be0, acc[0], 0, 0, 0);
    acc[1] = __builtin_amdgcn_mfma_f32_16x16x32_bf16(a0, be1, acc[1], 0, 0, 0);
    acc[2] = __builtin_amdgcn_mfma_f32_16x16x32_bf16(a0, be2, acc[2], 0, 0, 0);
    acc[3] = __builtin_amdgcn_mfma_f32_16x16x32_bf16(a0, be3, acc[3], 0, 0, 0);
    acc[4] = __builtin_amdgcn_mfma_f32_16x16x32_bf16(a1, be0, acc[4], 0, 0, 0);
    acc[5] = __builtin_amdgcn_mfma_f32_16x16x32_bf16(a1, be1, acc[5], 0, 0, 0);
    acc[6] = __builtin_amdgcn_mfma_f32_16x16x32_bf16(a1, be2, acc[6], 0, 0, 0);
    acc[7] = __builtin_amdgcn_mfma_f32_16x16x32_bf16(a1, be3, acc[7], 0, 0, 0);
  }

  // proj row indices (LDS reads independent of smem alias; prefetch pre-barrier)
  int sA[4], dA[4];
  #pragma unroll
  for (int t = 0; t < 4; ++t){ sA[t] = lsrc[t * 16 + lr]; dA[t] = ldst[t * 16 + lr]; }
  __syncthreads();   // edge_in reads done; alias LDS as H (64 x 264 bf16)

  // H[e][n] = gelu(D + b1[n] + PROJ_S[src][n] + PROJ_D[dst][n])
  {
    char* Hb = smem;
    #pragma unroll
    for (int c = 0; c < 2; ++c){
      int n = (c0 + c) * 16 + quad * 4;
      f32x4 bz = *(const f32x4*)(bias1 + n);
      f32x4 pv[4], qv[4];
      #pragma unroll
      for (int t = 0; t < 4; ++t){
        pv[t] = *(const f32x4*)(ps + (size_t)sA[t] * 256 + n);
        qv[t] = *(const f32x4*)(pd + (size_t)dA[t] * 256 + n);
      }
      #pragma unroll
      for (int t = 0; t < 4; ++t){
        int e = t * 16 + lr;
        f32x4 s4 = acc[c * 4 + t];
        float v0 = gelu_s(s4[0] + bz[0] + pv[t][0] + qv[t][0]);
        float v1 = gelu_s(s4[1] + bz[1] + pv[t][1] + qv[t][1]);
        float v2 = gelu_s(s4[2] + bz[2] + pv[t][2] + qv[t][2]);
        float v3 = gelu_s(s4[3] + bz[3] + pv[t][3] + qv[t][3]);
        uint2 p; p.x = pack_bf16(v0, v1); p.y = pack_bf16(v2, v3);
        *(uint2*)(Hb + e * 528 + n * 2) = p;
      }
    }
  }
  __syncthreads();

  // ---- GEMM2 (transposed): wave owns n-tiles {c2,c2+1} x e-tiles {eb,eb+16}
  int c2 = (w & 3) * 2;
  int eb = (w >> 2) * 32;
  f32x4 acc2[4];                    // [c*2 + t]
  #pragma unroll
  for (int i = 0; i < 4; ++i) acc2[i] = (f32x4){0.f, 0.f, 0.f, 0.f};
  const short8* w2f8 = (const short8*)w2f;
  #pragma unroll
  for (int s = 0; s < 8; ++s){
    short8 aa0 = w2f8[(s * 8 + c2 + 0) * 64 + lane];
    short8 aa1 = w2f8[(s * 8 + c2 + 1) * 64 + lane];
    short8 h0 = *(const short8*)(smem + (eb +  0 + lr) * 528 + s * 64 + qoff);
    short8 h1 = *(const short8*)(smem + (eb + 16 + lr) * 528 + s * 64 + qoff);
    acc2[0] = __builtin_amdgcn_mfma_f32_16x16x32_bf16(aa0, h0, acc2[0], 0, 0, 0);
    acc2[1] = __builtin_amdgcn_mfma_f32_16x16x32_bf16(aa0, h1, acc2[1], 0, 0, 0);
    acc2[2] = __builtin_amdgcn_mfma_f32_16x16x32_bf16(aa1, h0, acc2[2], 0, 0, 0);
    acc2[3] = __builtin_amdgcn_mfma_f32_16x16x32_bf16(aa1, h1, acc2[3], 0, 0, 0);
  }

  // output: lane writes 2 x f32x4 per edge (n0, n0+16) -> wave covers full
  // 128-B line of each of its 32 edge rows
  {
    int n0 = c2 * 16 + quad * 4;
    f32x4 bz0 = *(const f32x4*)(bias2 + n0);
    f32x4 bz1 = *(const f32x4*)(bias2 + n0 + 16);
    float* og = outp + (size_t)e0 * 128;
    #pragma unroll
    for (int t = 0; t < 2; ++t){
      int e = eb + t * 16 + lr;
      f32x4 v0, v1;
      v0[0] = acc2[t][0] + bz0[0]; v0[1] = acc2[t][1] + bz0[1];
      v0[2] = acc2[t][2] + bz0[2]; v0[3] = acc2[t][3] + bz0[3];
      v1[0] = acc2[2 + t][0] + bz1[0]; v1[1] = acc2[2 + t][1] + bz1[1];
      v1[2] = acc2[2 + t][2] + bz1[2]; v1[3] = acc2[2 + t][3] + bz1[3];
      *(f32x4*)(og + (size_t)e * 128 + n0)      = v0;
      *(f32x4*)(og + (size_t)e * 128 + n0 + 16) = v1;
    }
  }
}

extern "C" void kernel_launch(void* const* d_in, const int* in_sizes, int n_in,
                              void* d_out, int out_size, void* d_ws, size_t ws_size,
                              hipStream_t stream) {
  const float* emb    = (const float*)d_in[0];
  const float* ts     = (const float*)d_in[1];
  const float* coords = (const float*)d_in[2];
  const float* tf     = (const float*)d_in[3];
  const float* cf     = (const float*)d_in[4];
  const float* w1r    = (const float*)d_in[5];
  const float* b1r    = (const float*)d_in[6];
  const float* w2r    = (const float*)d_in[7];
  const float* b2r    = (const float*)d_in[8];
  const float* wg     = (const float*)d_in[9];
  const float* w1e    = (const float*)d_in[10];
  const float* b1e    = (const float*)d_in[11];
  const float* w2e    = (const float*)d_in[12];
  const float* b2e    = (const float*)d_in[13];
  const int* resi     = (const int*)d_in[14];
  const int* chain    = (const int*)d_in[15];
  const int* gia      = (const int*)d_in[16];
  const int* gib      = (const int*)d_in[17];
  const int* pid      = (const int*)d_in[18];

  char* ws = (char*)d_ws;
  float* RT            = (float*)(ws + WS_RT);
  unsigned short* REPB = (unsigned short*)(ws + WS_REPB);
  unsigned short* W1F  = (unsigned short*)(ws + WS_W1F);
  unsigned short* W2F  = (unsigned short*)(ws + WS_W2F);
  float* PS            = (float*)(ws + WS_PS);
  float* PD            = (float*)(ws + WS_PD);
  float* outp          = (float*)d_out;

  hipLaunchKernelGGL(prep_k, dim3(224), dim3(256), 0, stream,
                     emb, ts, tf, w1r, b1r, w2r, b2r, REPB,
                     coords, RT, wg, w1e, W1F, w2e, W2F);
  hipLaunchKernelGGL(proj_k, dim3(32), dim3(512), 0, stream,
                     REPB, W1F, PS, PD);
  hipLaunchKernelGGL(edge_k, dim3(2080), dim3(512), 0, stream,
                     RT, cf, resi, chain, gia, gib, pid, W1F, W2F, PS, PD,
                     b1e, b2e, outp);
}

// Round 2
// 218.400 us; speedup vs baseline: 1.0905x; 1.0648x over previous
//
#include <hip/hip_runtime.h>

// BindingFormer fused pipeline for MI355X (gfx950), round 8.
// r7 post-mortem: edge_k 90us, MfmaUtil 6.7%, VALUBusy 38% (~34us VALU),
// bank-conflict 3.6M. Feature phase was the VALU hog: slot = tid&7 mixes all
// 8 column-classes inside every wave -> all 5 branch bodies run exec-masked
// (~60 serial bodies/thread), plus 8x-redundant scalar Rs/Rd loads (12k
// scattered 4B loads/block). Fix: stage RT rows in LDS (128 coalesced
// f32x4x3 loads), then divergence-free class-phased fill (rope sincos x4,
// rbf x2, relrot/local x2, zeros x1 - all uniform bodies). H stride 528->560
// (528 gave 8-way ds_read_b128 conflicts: 4(lr+quad)%32; 560 -> 4(3lr+quad),
// 3lr bijective mod 8 -> conflict-free). bias1 folded into PROJ_S. prep_k
// swz stores vectorized (8x u16 scatter -> 1x 16B store).

typedef __attribute__((ext_vector_type(8))) short short8;  // 8 x bf16 (4 VGPRs)
typedef __attribute__((ext_vector_type(4))) float f32x4;   // MFMA accumulator

#define TWO_PI 6.283185307179586f
#define E_AB_TOT 131072

// ws layout (bytes)
#define WS_RT    0         // frames: 1024 x 12 f32            = 49152
#define WS_REPB  49152     // rep bf16 1024x256                = 524288
#define WS_W1F   573440    // swizzled W1' 19*16*64*8 bf16     = 311296
#define WS_W2F   884736    // swizzled W2  8*8*64*8 bf16       = 65536
#define WS_PS    950272    // PROJ_S f32 1024x256 (+bias1)     = 1048576
#define WS_PD    1998848   // PROJ_D f32 1024x256              = 1048576

__device__ __forceinline__ unsigned short f2bf(float x){
  unsigned int u = __float_as_uint(x);
  u += 0x7fffu + ((u >> 16) & 1u);            // RTNE
  return (unsigned short)(u >> 16);
}

// pack two f32 -> two bf16 (RTNE) in one u32 via v_perm
__device__ __forceinline__ unsigned int pack_bf16(float lo, float hi){
  unsigned int ul = __float_as_uint(lo), uh = __float_as_uint(hi);
  ul += 0x7fffu + ((ul >> 16) & 1u);
  uh += 0x7fffu + ((uh >> 16) & 1u);
  return __builtin_amdgcn_perm(uh, ul, 0x07060302);  // {uh[31:16], ul[31:16]}
}

// gelu tanh-form == x * sigmoid(2z), z = 0.79788456(x + 0.044715 x^3)
__device__ __forceinline__ float gelu_s(float x){
  float s = x * x;
  float w = x * __builtin_fmaf(-0.1029437f, s, -2.30220847f);
  float e = __builtin_exp2f(w);
  return x * __builtin_amdgcn_rcpf(1.0f + e);
}

// ---------- merged prep: rep MLP (blk 0-127) | frames (128-131) |
//            swz2 (132-147) | swz1 w/ inline wg1 (148-223) -------------------
__global__ __launch_bounds__(256) void prep_k(
    const float* __restrict__ emb, const float* __restrict__ ts,
    const float* __restrict__ tf,  const float* __restrict__ w1,
    const float* __restrict__ b1,  const float* __restrict__ w2,
    const float* __restrict__ b2,  unsigned short* __restrict__ repb,
    const float* __restrict__ coords, float* __restrict__ RT,
    const float* __restrict__ wg, const float* __restrict__ w1e,
    unsigned short* __restrict__ w1f,
    const float* __restrict__ w2e, unsigned short* __restrict__ w2f){
  __shared__ float xt[288 * 12];   // rep part only
  __shared__ float ht[256 * 12];
  int blk = blockIdx.x, tid = threadIdx.x;
  if (blk < 128){                   // ---- node MLP, 8 nodes/block ----
    int n0 = blk * 8;
    #pragma unroll
    for (int nd = 0; nd < 8; ++nd)
      xt[tid * 12 + nd] = emb[(n0 + nd) * 256 + tid];
    {
      int nd = tid >> 5, j = tid & 31;
      float ang = TWO_PI * ts[n0 + nd] * tf[j & 15];
      float s, c; __sincosf(ang, &s, &c);
      xt[(256 + j) * 12 + nd] = (j < 16) ? s : c;
    }
    __syncthreads();
    float acc[8];
    float bias1 = b1[tid];
    #pragma unroll
    for (int nd = 0; nd < 8; ++nd) acc[nd] = bias1;
    #pragma unroll 4
    for (int k = 0; k < 288; ++k){
      float w = w1[k * 256 + tid];
      f32x4 xa = *(const f32x4*)&xt[k * 12];
      f32x4 xb = *(const f32x4*)&xt[k * 12 + 4];
      acc[0] += xa[0]*w; acc[1] += xa[1]*w; acc[2] += xa[2]*w; acc[3] += xa[3]*w;
      acc[4] += xb[0]*w; acc[5] += xb[1]*w; acc[6] += xb[2]*w; acc[7] += xb[3]*w;
    }
    #pragma unroll
    for (int nd = 0; nd < 8; ++nd) ht[tid * 12 + nd] = gelu_s(acc[nd]);
    __syncthreads();
    float acc2[8];
    float bias2 = b2[tid];
    #pragma unroll
    for (int nd = 0; nd < 8; ++nd) acc2[nd] = bias2;
    #pragma unroll 4
    for (int k = 0; k < 256; ++k){
      float w = w2[k * 256 + tid];
      f32x4 ha = *(const f32x4*)&ht[k * 12];
      f32x4 hb = *(const f32x4*)&ht[k * 12 + 4];
      acc2[0] += ha[0]*w; acc2[1] += ha[1]*w; acc2[2] += ha[2]*w; acc2[3] += ha[3]*w;
      acc2[4] += hb[0]*w; acc2[5] += hb[1]*w; acc2[6] += hb[2]*w; acc2[7] += hb[3]*w;
    }
    #pragma unroll
    for (int nd = 0; nd < 8; ++nd)
      repb[(n0 + nd) * 256 + tid] = f2bf(acc2[nd] + xt[tid * 12 + nd]);
  } else if (blk < 132){            // ---- frames ----
    int n = (blk - 128) * 256 + tid;
    const float* p = coords + n * 9;
    float ax=p[0],ay=p[1],az=p[2], bx=p[3],by=p[4],bz=p[5], cx=p[6],cy=p[7],cz=p[8];
    float v1x=cx-bx, v1y=cy-by, v1z=cz-bz;
    float v2x=ax-bx, v2y=ay-by, v2z=az-bz;
    float n1 = sqrtf(v1x*v1x+v1y*v1y+v1z*v1z) + 1e-6f;
    float e1x=v1x/n1, e1y=v1y/n1, e1z=v1z/n1;
    float dp = e1x*v2x + e1y*v2y + e1z*v2z;
    float u2x=v2x-e1x*dp, u2y=v2y-e1y*dp, u2z=v2z-e1z*dp;
    float n2 = sqrtf(u2x*u2x+u2y*u2y+u2z*u2z) + 1e-6f;
    float e2x=u2x/n2, e2y=u2y/n2, e2z=u2z/n2;
    float* r = RT + n * 12;
    r[0]=e1x; r[1]=e2x; r[2]=e1y*e2z - e1z*e2y;
    r[3]=e1y; r[4]=e2y; r[5]=e1z*e2x - e1x*e2z;
    r[6]=e1z; r[7]=e2z; r[8]=e1x*e2y - e1y*e2x;
    r[9]=bx;  r[10]=by; r[11]=bz;
  } else if (blk < 148){            // ---- swz2: W2 (256x128) -> frag ----
    int u = (blk - 132) * 4 + (tid >> 6);   // 0..63
    int lane = tid & 63;
    int s = u >> 3, c = u & 7;
    int n  = c * 16 + (lane & 15);
    int kb = s * 32 + (lane >> 4) * 8;
    unsigned short* o = w2f + (((s * 8 + c) * 64) + lane) * 8;
    unsigned short vals[8];
    #pragma unroll
    for (int j = 0; j < 8; ++j)
      vals[j] = f2bf(w2e[(kb + j) * 128 + n]);
    *(uint4*)o = *(const uint4*)vals;
  } else {                          // ---- swz1: W1' (608x256) -> frag ----
    // K: [0:27 geom=wg@w1e[0:128] | 27:91 rope (w1e 128:192) | 91:96 zero
    //     | 96:352 rep_src (192:448) | 352:608 rep_dst (448:704)]
    int u = (blk - 148) * 4 + (tid >> 6);   // 0..303
    int lane = tid & 63;
    int s = u >> 4, c = u & 15;
    int n  = c * 16 + (lane & 15);
    int kb = s * 32 + (lane >> 4) * 8;
    unsigned short* o = w1f + (((s * 16 + c) * 64) + lane) * 8;
    unsigned short vals[8];
    for (int j = 0; j < 8; ++j){
      int k = kb + j;
      float val;
      if (k < 27){                  // inline wg1: w_geom[k] . w1e[0:128, n]
        val = 0.f;
        for (int j2 = 0; j2 < 128; ++j2) val += wg[k * 128 + j2] * w1e[j2 * 256 + n];
      }
      else if (k < 91)  val = w1e[(128 + k - 27)  * 256 + n];
      else if (k < 96)  val = 0.f;
      else if (k < 352) val = w1e[(192 + k - 96)  * 256 + n];
      else              val = w1e[(448 + k - 352) * 256 + n];
      vals[j] = f2bf(val);
    }
    *(uint4*)o = *(const uint4*)vals;
  }
}

// ---------- proj_k: per-node projections PROJ_S/PROJ_D = REP @ W1_{src,dst} --
// Reuses w1f A-frags (k-tiles 3..10 = rep_src, 11..18 = rep_dst) and REPB rows
// as B-frags. grid 32: blk = nt*2 + part. Output f32 [1024][256].
// bias1 is folded into PROJ_S (part==0) so the edge epilogue skips it.
__global__ __launch_bounds__(512) void proj_k(
    const unsigned short* __restrict__ repb,
    const unsigned short* __restrict__ w1f,
    const float* __restrict__ b1e,
    float* __restrict__ ps, float* __restrict__ pd)
{
  int part = blockIdx.x & 1;        // 0 = src (s 3..10), 1 = dst (s 11..18)
  int nt   = blockIdx.x >> 1;      // node tile, 64 nodes
  int tid  = threadIdx.x, w = tid >> 6, lane = tid & 63;
  int c0 = w * 2, lr = lane & 15, quad = lane >> 4;
  int n0g = nt * 64;
  const short8* w1f8 = (const short8*)w1f;
  f32x4 acc[8];
  #pragma unroll
  for (int i = 0; i < 8; ++i) acc[i] = (f32x4){0.f, 0.f, 0.f, 0.f};
  int sb = 3 + part * 8;
  #pragma unroll
  for (int s = 0; s < 8; ++s){
    short8 a0 = w1f8[((sb + s) * 16 + c0 + 0) * 64 + lane];
    short8 a1 = w1f8[((sb + s) * 16 + c0 + 1) * 64 + lane];
    #pragma unroll
    for (int t = 0; t < 4; ++t){
      short8 b = *(const short8*)(repb + (n0g + t * 16 + lr) * 256 + s * 32 + quad * 8);
      acc[t]     = __builtin_amdgcn_mfma_f32_16x16x32_bf16(a0, b, acc[t],     0, 0, 0);
      acc[4 + t] = __builtin_amdgcn_mfma_f32_16x16x32_bf16(a1, b, acc[4 + t], 0, 0, 0);
    }
  }
  float* out = part ? pd : ps;
  #pragma unroll
  for (int c = 0; c < 2; ++c){
    int n = (c0 + c) * 16 + quad * 4;
    f32x4 add = (f32x4){0.f, 0.f, 0.f, 0.f};
    if (!part) add = *(const f32x4*)(b1e + n);
    #pragma unroll
    for (int t = 0; t < 4; ++t){
      f32x4 v = acc[c * 4 + t];
      v[0] += add[0]; v[1] += add[1]; v[2] += add[2]; v[3] += add[3];
      *(f32x4*)(out + (n0g + t * 16 + lr) * 256 + n) = v;
    }
  }
}

// ---------- fused edge kernel: 64 edges/block, 512 thr (8 waves) -----------
// TRANSPOSED: mfma(A=weight frag, B=edge/H row frag) -> D[col=edge, row=n].
// Feature fill is class-phased & divergence-free; RT rows staged in LDS.
__global__ __launch_bounds__(512, 4) void edge_k(
    const float* __restrict__ RT,  const float* __restrict__ cf,
    const int* __restrict__ resi, const int* __restrict__ chain,
    const int* __restrict__ gia,  const int* __restrict__ gib,
    const int* __restrict__ pid,
    const unsigned short* __restrict__ w1f, const unsigned short* __restrict__ w2f,
    const float* __restrict__ ps, const float* __restrict__ pd,
    const float* __restrict__ bias2,
    float* __restrict__ outp)
{
  // phase1: edge_in 64 x 208 B (96 bf16 + pad); phase2 alias: H 64 x 560 B
  __shared__ __align__(16) char smem[35840];
  __shared__ __align__(16) float rtbuf[128][12];   // 64 src rows, 64 dst rows
  __shared__ float scD[64];                         // disp
  __shared__ float scI[64];                         // rope scale (chain mask)
  __shared__ int lsrc[64];
  __shared__ int ldst[64];

  int tid = threadIdx.x;
  int e0  = blockIdx.x * 64;

  if (tid < 64){                    // indices + per-edge scalars
    int e = e0 + tid, s_, d_;
    if (e < E_AB_TOT){ s_ = gia[e]; d_ = gib[e]; }
    else {
      int i = e - E_AB_TOT;
      int b = i >> 10, w_ = i & 1023;
      s_ = pid[b * 32 + (w_ >> 5)];
      d_ = pid[b * 32 + (w_ & 31)];
    }
    lsrc[tid] = s_; ldst[tid] = d_;
    float disp = ((float)resi[s_] - (float)resi[d_]) * 0.125f;
    scD[tid] = disp;
    scI[tid] = (chain[s_] == chain[d_]) ? 1.f / (fabsf(disp) + 1.f) : 0.f;
  } else if (tid < 192){            // RT staging: 128 rows x 48 B, vectorized
    int r  = tid - 64;              // 0..127 : 0..63 = src rows, 64..127 = dst
    int e  = e0 + (r & 63);
    int node;
    if (e < E_AB_TOT){ node = (r < 64) ? gia[e] : gib[e]; }
    else {
      int i = e - E_AB_TOT;
      int b = i >> 10, w_ = i & 1023;
      node = (r < 64) ? pid[b * 32 + (w_ >> 5)] : pid[b * 32 + (w_ & 31)];
    }
    const f32x4* p = (const f32x4*)(RT + node * 12);
    f32x4* q = (f32x4*)(&rtbuf[r][0]);
    q[0] = p[0]; q[1] = p[1]; q[2] = p[2];
  }
  __syncthreads();

  // ---- divergence-free feature fill (cols 0..95 of edge_in) ----
  {
    // rope: 2048 (edge, freq) pairs, one sincos fills sin+cos cols
    #pragma unroll
    for (int it = 0; it < 4; ++it){
      int v = it * 512 + tid, ed = v >> 5, j = v & 31;
      float ang = TWO_PI * scD[ed] * cf[j];
      float s, c; __sincosf(ang, &s, &c);
      float inv = scI[ed];
      unsigned short* row = (unsigned short*)(smem + ed * 208);
      row[27 + j] = f2bf(s * inv);
      row[59 + j] = f2bf(c * inv);
    }
    // rbf: 64 edges x 15 centers (c==15 lanes idle)
    #pragma unroll
    for (int it = 0; it < 2; ++it){
      int v = it * 512 + tid, ed = v >> 4, c = v & 15;
      float tx = rtbuf[64 + ed][9]  - rtbuf[ed][9];
      float ty = rtbuf[64 + ed][10] - rtbuf[ed][10];
      float tz = rtbuf[64 + ed][11] - rtbuf[ed][11];
      float dist = sqrtf(tx*tx + ty*ty + tz*tz + 1e-6f);
      if (c < 15){
        float z = (dist - (float)c * (20.f / 14.f)) * (15.f / 20.f);
        ((unsigned short*)(smem + ed * 208))[c] = f2bf(__expf(-0.5f * z * z));
      }
    }
    // relrot (9) + local (3): cols 15..26
    #pragma unroll
    for (int it = 0; it < 2; ++it){
      int v = it * 512 + tid, ed = v >> 4, cc = v & 15;
      if (cc < 12){
        const float* Rs = &rtbuf[ed][0];
        const float* Rd = &rtbuf[64 + ed][0];
        float val;
        if (cc < 9){
          int a  = (cc >= 6) ? 2 : ((cc >= 3) ? 1 : 0);
          int b_ = cc - 3 * a;
          val = Rs[a]*Rd[b_] + Rs[3+a]*Rd[3+b_] + Rs[6+a]*Rd[6+b_];
        } else {
          int k = cc - 9;
          float tx = Rd[9]-Rs[9], ty = Rd[10]-Rs[10], tz = Rd[11]-Rs[11];
          float dist = sqrtf(tx*tx + ty*ty + tz*tz + 1e-6f);
          val = (Rs[k]*tx + Rs[3+k]*ty + Rs[6+k]*tz) / (dist + 1.f);
        }
        ((unsigned short*)(smem + ed * 208))[15 + cc] = f2bf(val);
      }
    }
    // zeros: cols 91..98 (96..98 are pad, harmless)
    {
      int ed = tid >> 3, c8 = tid & 7;
      ((unsigned short*)(smem + ed * 208))[91 + c8] = 0;
    }
  }
  __syncthreads();

  // ---- GEMM1 (transposed): D[n][e] = W1_feat^T x edge_in^T, K=96 ----
  int w    = tid >> 6, lane = tid & 63;
  int c0   = w * 2;                 // 2 n-tiles per wave
  int lr   = lane & 15;             // edge within e-tile
  int quad = lane >> 4, qoff = quad * 16;
  f32x4 acc[8];                     // [c*4 + etile]
  #pragma unroll
  for (int i = 0; i < 8; ++i) acc[i] = (f32x4){0.f, 0.f, 0.f, 0.f};
  const short8* w1f8 = (const short8*)w1f;

  #pragma unroll
  for (int s = 0; s < 3; ++s){
    short8 a0 = w1f8[(s * 16 + c0 + 0) * 64 + lane];
    short8 a1 = w1f8[(s * 16 + c0 + 1) * 64 + lane];
    short8 be0 = *(const short8*)(smem + ( 0 + lr) * 208 + s * 64 + qoff);
    short8 be1 = *(const short8*)(smem + (16 + lr) * 208 + s * 64 + qoff);
    short8 be2 = *(const short8*)(smem + (32 + lr) * 208 + s * 64 + qoff);
    short8 be3 = *(const short8*)(smem + (48 + lr) * 208 + s * 64 + qoff);
    acc[0] = __builtin_amdgcn_mfma_f32_16x16x32_bf16(a0, be0, acc[0], 0, 0, 0);
    acc[1] = __builtin_amdgcn_mfma_f32_16x16x32_bf16(a0, be1, acc[1], 0, 0, 0);
    acc[2] = __builtin_amdgcn_mfma_f32_16x16x32_bf16(a0, be2, acc[2], 0, 0, 0);
    acc[3] = __builtin_amdgcn_mfma_f32_16x16x32_bf16(a0, be3, acc[3], 0, 0, 0);
    acc[4] = __builtin_amdgcn_mfma_f32_16x16x32_bf16(a1, be0, acc[4], 0, 0, 0);
    acc[5] = __builtin_amdgcn_mfma_f32_16x16x32_bf16(a1, be1, acc[5], 0, 0, 0);
    acc[6] = __builtin_amdgcn_mfma_f32_16x16x32_bf16(a1, be2, acc[6], 0, 0, 0);
    acc[7] = __builtin_amdgcn_mfma_f32_16x16x32_bf16(a1, be3, acc[7], 0, 0, 0);
  }
  __syncthreads();   // edge_in reads done; alias LDS as H (64 x 280 bf16)

  // H[e][n] = gelu(D + PROJ_S[src][n] + PROJ_D[dst][n])   (b1 inside PROJ_S)
  {
    char* Hb = smem;
    #pragma unroll
    for (int c = 0; c < 2; ++c){
      int n = (c0 + c) * 16 + quad * 4;
      f32x4 pv[4], qv[4];
      #pragma unroll
      for (int t = 0; t < 4; ++t){
        pv[t] = *(const f32x4*)(ps + (size_t)lsrc[t * 16 + lr] * 256 + n);
        qv[t] = *(const f32x4*)(pd + (size_t)ldst[t * 16 + lr] * 256 + n);
      }
      #pragma unroll
      for (int t = 0; t < 4; ++t){
        int e = t * 16 + lr;
        f32x4 s4 = acc[c * 4 + t];
        float v0 = gelu_s(s4[0] + pv[t][0] + qv[t][0]);
        float v1 = gelu_s(s4[1] + pv[t][1] + qv[t][1]);
        float v2 = gelu_s(s4[2] + pv[t][2] + qv[t][2]);
        float v3 = gelu_s(s4[3] + pv[t][3] + qv[t][3]);
        uint2 p; p.x = pack_bf16(v0, v1); p.y = pack_bf16(v2, v3);
        *(uint2*)(Hb + e * 560 + n * 2) = p;
      }
    }
  }
  __syncthreads();

  // ---- GEMM2 (transposed): wave owns n-tiles {c2,c2+1} x e-tiles {eb,eb+16}
  int c2 = (w & 3) * 2;
  int eb = (w >> 2) * 32;
  f32x4 acc2[4];                    // [c*2 + t]
  #pragma unroll
  for (int i = 0; i < 4; ++i) acc2[i] = (f32x4){0.f, 0.f, 0.f, 0.f};
  const short8* w2f8 = (const short8*)w2f;
  #pragma unroll
  for (int s = 0; s < 8; ++s){
    short8 aa0 = w2f8[(s * 8 + c2 + 0) * 64 + lane];
    short8 aa1 = w2f8[(s * 8 + c2 + 1) * 64 + lane];
    short8 h0 = *(const short8*)(smem + (eb +  0 + lr) * 560 + s * 64 + qoff);
    short8 h1 = *(const short8*)(smem + (eb + 16 + lr) * 560 + s * 64 + qoff);
    acc2[0] = __builtin_amdgcn_mfma_f32_16x16x32_bf16(aa0, h0, acc2[0], 0, 0, 0);
    acc2[1] = __builtin_amdgcn_mfma_f32_16x16x32_bf16(aa0, h1, acc2[1], 0, 0, 0);
    acc2[2] = __builtin_amdgcn_mfma_f32_16x16x32_bf16(aa1, h0, acc2[2], 0, 0, 0);
    acc2[3] = __builtin_amdgcn_mfma_f32_16x16x32_bf16(aa1, h1, acc2[3], 0, 0, 0);
  }

  // output: lane writes 2 x f32x4 per edge (n0, n0+16) -> wave covers full
  // 128-B line of each of its 32 edge rows
  {
    int n0 = c2 * 16 + quad * 4;
    f32x4 bz0 = *(const f32x4*)(bias2 + n0);
    f32x4 bz1 = *(const f32x4*)(bias2 + n0 + 16);
    float* og = outp + (size_t)e0 * 128;
    #pragma unroll
    for (int t = 0; t < 2; ++t){
      int e = eb + t * 16 + lr;
      f32x4 v0, v1;
      v0[0] = acc2[t][0] + bz0[0]; v0[1] = acc2[t][1] + bz0[1];
      v0[2] = acc2[t][2] + bz0[2]; v0[3] = acc2[t][3] + bz0[3];
      v1[0] = acc2[2 + t][0] + bz1[0]; v1[1] = acc2[2 + t][1] + bz1[1];
      v1[2] = acc2[2 + t][2] + bz1[2]; v1[3] = acc2[2 + t][3] + bz1[3];
      *(f32x4*)(og + (size_t)e * 128 + n0)      = v0;
      *(f32x4*)(og + (size_t)e * 128 + n0 + 16) = v1;
    }
  }
}

extern "C" void kernel_launch(void* const* d_in, const int* in_sizes, int n_in,
                              void* d_out, int out_size, void* d_ws, size_t ws_size,
                              hipStream_t stream) {
  const float* emb    = (const float*)d_in[0];
  const float* ts     = (const float*)d_in[1];
  const float* coords = (const float*)d_in[2];
  const float* tf     = (const float*)d_in[3];
  const float* cf     = (const float*)d_in[4];
  const float* w1r    = (const float*)d_in[5];
  const float* b1r    = (const float*)d_in[6];
  const float* w2r    = (const float*)d_in[7];
  const float* b2r    = (const float*)d_in[8];
  const float* wg     = (const float*)d_in[9];
  const float* w1e    = (const float*)d_in[10];
  const float* b1e    = (const float*)d_in[11];
  const float* w2e    = (const float*)d_in[12];
  const float* b2e    = (const float*)d_in[13];
  const int* resi     = (const int*)d_in[14];
  const int* chain    = (const int*)d_in[15];
  const int* gia      = (const int*)d_in[16];
  const int* gib      = (const int*)d_in[17];
  const int* pid      = (const int*)d_in[18];

  char* ws = (char*)d_ws;
  float* RT            = (float*)(ws + WS_RT);
  unsigned short* REPB = (unsigned short*)(ws + WS_REPB);
  unsigned short* W1F  = (unsigned short*)(ws + WS_W1F);
  unsigned short* W2F  = (unsigned short*)(ws + WS_W2F);
  float* PS            = (float*)(ws + WS_PS);
  float* PD            = (float*)(ws + WS_PD);
  float* outp          = (float*)d_out;

  hipLaunchKernelGGL(prep_k, dim3(224), dim3(256), 0, stream,
                     emb, ts, tf, w1r, b1r, w2r, b2r, REPB,
                     coords, RT, wg, w1e, W1F, w2e, W2F);
  hipLaunchKernelGGL(proj_k, dim3(32), dim3(512), 0, stream,
                     REPB, W1F, b1e, PS, PD);
  hipLaunchKernelGGL(edge_k, dim3(2080), dim3(512), 0, stream,
                     RT, cf, resi, chain, gia, gib, pid, W1F, W2F, PS, PD,
                     b2e, outp);
}